// Round 1
// baseline (162.055 us; speedup 1.0000x reference)
//
#include <hip/hip_runtime.h>
#include <math.h>

#define N_G   64
#define M_N   32
#define FEAT  256
#define POSD  6
#define D     262
#define MSG   128
#define NCLS  7

#define KA_S  424       // LDS buf row stride (shorts): [mv 128 | h 262 | pad]
#define KHW   288       // weight K window over h (262 -> 288)
#define KFULL 416       // full concat K
#define PSTR  320       // paL/pbL row stride (shorts), covers c16*4+64k up to 316

// packed weight sizes (shorts)
#define S_PROJ (528*288)
#define S_MSG  (128*288)
#define S_RZ   (544*416)
#define S_XN   (272*128)
#define S_HN   (272*288)
#define S_RO   (128*288)
#define S_RO2  (16*128)

// workspace float offsets
#define O_WPROJ 0u
#define O_WMSG  76032u
#define O_WRZ   94464u
#define O_WXN   207616u
#define O_WHN   225024u
#define O_WRO   264192u
#define O_WRO2  282624u
#define O_GB    283648u   // 1088 fp32 gate biases [br|bz|bxn|bhn] x 272

typedef __attribute__((ext_vector_type(8))) short short8;
typedef __attribute__((ext_vector_type(4))) short short4v;
typedef __attribute__((ext_vector_type(4))) float floatx4;

#define MFMA __builtin_amdgcn_mfma_f32_16x16x32_bf16

__device__ __forceinline__ short f2bf(float f) {
    union { float f; unsigned u; } v; v.f = f;
    unsigned r = v.u + 0x7FFF + ((v.u >> 16) & 1);   // RNE
    return (short)(r >> 16);
}
__device__ __forceinline__ float bf2f(short s) {
    union { float f; unsigned u; } v;
    v.u = ((unsigned)(unsigned short)s) << 16;
    return v.f;
}
// fast sigmoid/tanh: v_exp_f32 + v_rcp_f32 (~1e-6 rel err, vs bf16-path 5e-3)
__device__ __forceinline__ float sigf(float x) {
    return __builtin_amdgcn_rcpf(1.f + __expf(-x));
}
__device__ __forceinline__ float tanh_fast(float x) {
    float e = __expf(-2.f * fabsf(x));
    float t = (1.f - e) * __builtin_amdgcn_rcpf(1.f + e);
    return copysignf(t, x);
}

// ---------------------------------------------------------------------------
// prep: pack all weights bf16 [n][k] (B^T) with padded/zeroed windows + biases
// ---------------------------------------------------------------------------
__global__ void prep_kernel(const float* __restrict__ w1, const float* __restrict__ msg_w,
                            const float* __restrict__ w_ih, const float* __restrict__ w_hh,
                            const float* __restrict__ ro_w1, const float* __restrict__ ro_w2,
                            const float* __restrict__ b_ih, const float* __restrict__ b_hh,
                            float* __restrict__ ws)
{
    short* wproj = (short*)(ws + O_WPROJ);
    short* wmsg  = (short*)(ws + O_WMSG);
    short* wrz   = (short*)(ws + O_WRZ);
    short* wxn   = (short*)(ws + O_WXN);
    short* whn   = (short*)(ws + O_WHN);
    short* wro   = (short*)(ws + O_WRO);
    short* wro2  = (short*)(ws + O_WRO2);
    float* gb    = ws + O_GB;
    const int TOT_S = S_PROJ + S_MSG + S_RZ + S_XN + S_HN + S_RO + S_RO2;
    const int TOTAL = TOT_S + 1088;
    for (int i = blockIdx.x * blockDim.x + threadIdx.x; i < TOTAL;
         i += gridDim.x * blockDim.x) {
        int idx = i;
        if (idx < S_PROJ) {                       // [528][288]
            int n = idx / 288, k = idx % 288;
            float v = 0.f;
            if (k < D && n < 524)
                v = (n < D) ? w1[n * 524 + k] : w1[(n - D) * 524 + D + k];
            wproj[idx] = f2bf(v);
            continue;
        }
        idx -= S_PROJ;
        if (idx < S_MSG) {                        // [128][288]
            int n = idx / 288, k = idx % 288;
            wmsg[idx] = f2bf(k < D ? msg_w[n * D + k] : 0.f);
            continue;
        }
        idx -= S_MSG;
        if (idx < S_RZ) {                         // [544][416]: rows 0..271 r, 272..543 z
            int g = idx / 416, k = idx % 416;
            int gi = (g < 272) ? 0 : 1;
            int d = g - gi * 272;
            float v = 0.f;
            if (d < D) {
                int row = gi * D + d;
                if (k < 128)            v = w_ih[row * MSG + k];
                else if (k < 128 + D)   v = w_hh[row * D + (k - 128)];
            }
            wrz[idx] = f2bf(v);
            continue;
        }
        idx -= S_RZ;
        if (idx < S_XN) {                         // [272][128]
            int d = idx / 128, k = idx % 128;
            wxn[idx] = f2bf(d < D ? w_ih[(2 * D + d) * MSG + k] : 0.f);
            continue;
        }
        idx -= S_XN;
        if (idx < S_HN) {                         // [272][288]
            int d = idx / 288, k = idx % 288;
            whn[idx] = f2bf((d < D && k < D) ? w_hh[(2 * D + d) * D + k] : 0.f);
            continue;
        }
        idx -= S_HN;
        if (idx < S_RO) {                         // [128][288]
            int n = idx / 288, k = idx % 288;
            wro[idx] = f2bf(k < D ? ro_w1[n * D + k] : 0.f);
            continue;
        }
        idx -= S_RO;
        if (idx < S_RO2) {                        // [16][128]
            int n = idx / 128, k = idx % 128;
            wro2[idx] = f2bf(n < NCLS ? ro_w2[n * MSG + k] : 0.f);
            continue;
        }
        idx -= S_RO2;
        {                                          // gate biases [4][272]
            int seg = idx / 272, d = idx % 272;
            float v = 0.f;
            if (d < D) {
                if (seg == 0)      v = b_ih[d] + b_hh[d];
                else if (seg == 1) v = b_ih[D + d] + b_hh[D + d];
                else if (seg == 2) v = b_ih[2 * D + d];
                else               v = b_hh[2 * D + d];
            }
            gb[idx] = v;
        }
    }
}

// ---------------------------------------------------------------------------
// fused: one block per graph; full forward in LDS.
// 1024 threads = 16 waves = 4 waves/SIMD (was 8 waves = 2/SIMD: latency-bound).
// ---------------------------------------------------------------------------
__global__ __launch_bounds__(1024) void fused_kernel(
    const float* __restrict__ nodes, const float* __restrict__ pos,
    const int* __restrict__ nrec_g,
    const float* __restrict__ b1g, const float* __restrict__ w2g,
    const float* __restrict__ b2g, const float* __restrict__ msg_bg,
    const float* __restrict__ ro_b1g, const float* __restrict__ ro_b2g,
    const float* __restrict__ ws,
    float* __restrict__ att_out, float* __restrict__ pred)
{
    const short* Wproj = (const short*)(ws + O_WPROJ);
    const short* Wmsg  = (const short*)(ws + O_WMSG);
    const short* Wrz   = (const short*)(ws + O_WRZ);
    const short* Wxn   = (const short*)(ws + O_WXN);
    const short* Whn   = (const short*)(ws + O_WHN);
    const short* Wro   = (const short*)(ws + O_WRO);
    const short* Wro2  = (const short*)(ws + O_WRO2);
    const float* gb    = ws + O_GB;

    __shared__ __align__(16) short bufA[32 * KA_S];
    __shared__ __align__(16) short bufB[32 * KA_S];
    __shared__ __align__(16) short paL[32 * PSTR];
    __shared__ __align__(16) short pbL[32 * PSTR];
    __shared__ __align__(16) short attL[32 * 40];   // bf16 A-layout for mix
    __shared__ __align__(16) short msgT[128 * 40];  // bf16 B^T layout for mix
    __shared__ __align__(16) short hidL[32 * 136];
    __shared__ __align__(16) float b1L[PSTR], w2L[PSTR];

    const int b = blockIdx.x;
    const int tid = threadIdx.x;
    const int wave = tid >> 6, lane = tid & 63;
    const int quad = lane >> 4, lrow = lane & 15;
    const int nr = nrec_g[b];

    // ---- P0: load h0 bf16, zero pads, stage padded b1/w2 ----
    for (int idx = tid; idx < 32 * 64; idx += 1024) {         // nodes (float4)
        int w = idx >> 6, c4 = idx & 63;
        floatx4 v = *(const floatx4*)(nodes + ((size_t)(b * 32 + w)) * FEAT + c4 * 4);
        short4v s; s[0] = f2bf(v[0]); s[1] = f2bf(v[1]); s[2] = f2bf(v[2]); s[3] = f2bf(v[3]);
        *(short4v*)(bufA + w * KA_S + 128 + c4 * 4) = s;
    }
    for (int idx = tid; idx < 32 * POSD; idx += 1024) {       // pos
        int w = idx / POSD, c = idx % POSD;
        bufA[w * KA_S + 128 + FEAT + c] = f2bf(pos[((size_t)(b * 32 + w)) * POSD + c]);
    }
    for (int idx = tid; idx < 32 * 34; idx += 1024) {         // col pads 390..423
        int w = idx / 34, c = idx % 34;
        bufA[w * KA_S + 390 + c] = 0;
        bufB[w * KA_S + 390 + c] = 0;
    }
    for (int idx = tid; idx < 32 * (PSTR - D); idx += 1024) { // pa/pb pads 262..319
        int w = idx / (PSTR - D), c = idx % (PSTR - D);
        paL[w * PSTR + D + c] = 0;
        pbL[w * PSTR + D + c] = 0;
    }
    for (int d = tid; d < PSTR; d += 1024) {
        b1L[d] = (d < D) ? b1g[d] : 0.f;
        w2L[d] = (d < D) ? w2g[d] : 0.f;
    }
    __syncthreads();

    // ---- P1: combined GEMM over h0 ----
    //   tiles 0..32 : proj = h0 @ Wproj^T (528 cols) -> paL/pbL bf16
    //   tiles 33..40: round-0 msg = h0 @ Wmsg^T + msg_b -> msgT bf16
    // (round-0 msg depends only on h0, so it rides the same K=288 GEMM and
    //  removes one phase + one barrier from the serial chain)
    for (int s = wave; s < 41; s += 16) {
        floatx4 acc0 = {}, acc1 = {};
        const short* bw = (s < 33)
            ? Wproj + (s * 16 + lrow) * KHW + quad * 8
            : Wmsg + ((s - 33) * 16 + lrow) * KHW + quad * 8;
        const short* ap = bufA + lrow * KA_S + 128 + quad * 8;
        for (int kk = 0; kk < 9; ++kk) {
            short8 a0 = *(const short8*)(ap + kk * 32);
            short8 a1 = *(const short8*)(ap + 16 * KA_S + kk * 32);
            short8 bv = *(const short8*)(bw + kk * 32);
            acc0 = MFMA(a0, bv, acc0, 0, 0, 0);
            acc1 = MFMA(a1, bv, acc1, 0, 0, 0);
        }
        if (s < 33) {
            int col = s * 16 + lrow;
#pragma unroll
            for (int rr = 0; rr < 4; ++rr) {
                int r0 = quad * 4 + rr;
                if (col < D) {
                    paL[r0 * PSTR + col] = f2bf(acc0[rr]);
                    paL[(r0 + 16) * PSTR + col] = f2bf(acc1[rr]);
                } else if (col < 2 * D) {
                    pbL[r0 * PSTR + (col - D)] = f2bf(acc0[rr]);
                    pbL[(r0 + 16) * PSTR + (col - D)] = f2bf(acc1[rr]);
                }
            }
        } else {
            int col = (s - 33) * 16 + lrow;
            float bias = msg_bg[col];
#pragma unroll
            for (int rr = 0; rr < 4; ++rr) {
                msgT[col * 40 + quad * 4 + rr] = f2bf(acc0[rr] + bias);
                msgT[col * 40 + 16 + quad * 4 + rr] = f2bf(acc1[rr] + bias);
            }
        }
    }
    __syncthreads();

    // ---- P2: attention — 64 groups of 16 lanes, each does 16 j's ----
    {
        const int grp = tid >> 4;          // 0..63
        const int i   = grp >> 1;          // receiver node
        const int jh  = (grp & 1) * 16;    // j-half base
        const int c16 = tid & 15;
        const float b2v = b2g[0];
        float pav[5][4], b1v[5][4], w2v[5][4];
#pragma unroll
        for (int k = 0; k < 5; ++k) {
            int dbase = c16 * 4 + 64 * k;
            short4v p = *(const short4v*)(paL + i * PSTR + dbase);
            floatx4 bb = *(const floatx4*)(b1L + dbase);
            floatx4 ww = *(const floatx4*)(w2L + dbase);
#pragma unroll
            for (int e = 0; e < 4; ++e) {
                pav[k][e] = bf2f(p[e]); b1v[k][e] = bb[e]; w2v[k][e] = ww[e];
            }
        }
        // c0 = invalid-pair logit
        float p0 = 0.f;
#pragma unroll
        for (int k = 0; k < 5; ++k)
#pragma unroll
            for (int e = 0; e < 4; ++e)
                p0 += fmaxf(b1v[k][e], 0.f) * w2v[k][e];
        p0 += __shfl_down(p0, 8, 16); p0 += __shfl_down(p0, 4, 16);
        p0 += __shfl_down(p0, 2, 16); p0 += __shfl_down(p0, 1, 16);
        float c0 = sigf(p0 + b2v);
        const bool vi = i < nr;
        for (int jj = 0; jj < 16; ++jj) {
            int j = jh + jj;
            float a;
            if (j < nr && vi) {
                const short* pb = pbL + j * PSTR + c16 * 4;
                float s = 0.f;
#pragma unroll
                for (int k = 0; k < 5; ++k) {
                    short4v q = *(const short4v*)(pb + 64 * k);
#pragma unroll
                    for (int e = 0; e < 4; ++e) {
                        float v = pav[k][e] + bf2f(q[e]) + b1v[k][e];
                        s += fmaxf(v, 0.f) * w2v[k][e];
                    }
                }
                s += __shfl_down(s, 8, 16); s += __shfl_down(s, 4, 16);
                s += __shfl_down(s, 2, 16); s += __shfl_down(s, 1, 16);
                a = sigf(s + b2v);
            } else {
                a = c0;
            }
            if (c16 == 0) {
                att_out[((size_t)(b * 32 + i)) * 32 + j] = a;
                attL[i * 40 + j] = f2bf((j < nr) ? a : 0.f);
            }
        }
    }
    __syncthreads();

    // ---- two message-passing rounds ----
    for (int rnd = 0; rnd < 2; ++rnd) {
        short* src = rnd ? bufB : bufA;
        short* dst = rnd ? bufA : bufB;

        // msg = h @ Wmsg^T + msg_b -> msgT bf16 (round 0 done in P1)
        if (rnd) {
            int s = wave >> 1, mi = wave & 1;
            floatx4 acc = {};
            const short* bw = Wmsg + (s * 16 + lrow) * KHW + quad * 8;
            const short* ap = src + (mi * 16 + lrow) * KA_S + 128 + quad * 8;
            for (int kk = 0; kk < 9; ++kk) {
                short8 a0 = *(const short8*)(ap + kk * 32);
                short8 bv = *(const short8*)(bw + kk * 32);
                acc = MFMA(a0, bv, acc, 0, 0, 0);
            }
            int col = s * 16 + lrow;
            float bias = msg_bg[col];
#pragma unroll
            for (int rr = 0; rr < 4; ++rr)
                msgT[col * 40 + mi * 16 + quad * 4 + rr] = f2bf(acc[rr] + bias);
            __syncthreads();
        }

        // mix via MFMA: mv = attL(32x32) @ msg -> bf16 src cols 0..127
        {
            int mi = wave & 1, ng = wave >> 1;     // ng 0..7: 16 cols each
            short8 afrag = *(const short8*)(attL + (mi * 16 + lrow) * 40 + quad * 8);
            floatx4 acc = {};
            short8 bf0 = *(const short8*)(msgT + (ng * 16 + lrow) * 40 + quad * 8);
            acc = MFMA(afrag, bf0, acc, 0, 0, 0);
#pragma unroll
            for (int rr = 0; rr < 4; ++rr) {
                int m = mi * 16 + quad * 4 + rr;
                src[m * KA_S + ng * 16 + lrow] = f2bf(acc[rr]);
            }
        }
        __syncthreads();

        // GRU: fused [gx|gh] GEMM + elementwise, writes dst h-cols.
        // 34 half-units (17 d-tiles x 2 row-halves) over 16 waves.
        for (int u = wave; u < 34; u += 16) {
            int s = u >> 1, half = u & 1;
            floatx4 aR = {}, aZ = {}, aN = {}, aH = {};
            const short* ap  = src + (half * 16 + lrow) * KA_S + quad * 8;
            const short* bpr = Wrz + (s * 16 + lrow) * KFULL + quad * 8;
            const short* bpz = Wrz + (272 + s * 16 + lrow) * KFULL + quad * 8;
            const short* bpx = Wxn + (s * 16 + lrow) * 128 + quad * 8;
            const short* bph = Whn + (s * 16 + lrow) * KHW + quad * 8;
            for (int kk = 0; kk < 13; ++kk) {
                short8 a0 = *(const short8*)(ap + kk * 32);
                short8 br = *(const short8*)(bpr + kk * 32);
                short8 bz = *(const short8*)(bpz + kk * 32);
                aR = MFMA(a0, br, aR, 0, 0, 0);
                aZ = MFMA(a0, bz, aZ, 0, 0, 0);
                if (kk < 4) {
                    short8 bx = *(const short8*)(bpx + kk * 32);
                    aN = MFMA(a0, bx, aN, 0, 0, 0);
                } else {
                    short8 bh = *(const short8*)(bph + (kk - 4) * 32);
                    aH = MFMA(a0, bh, aH, 0, 0, 0);
                }
            }
            int d = s * 16 + lrow;
            if (d < D) {
                float bgr = gb[d], bgz = gb[272 + d];
                float bxv = gb[544 + d], bhv = gb[816 + d];
#pragma unroll
                for (int rr = 0; rr < 4; ++rr) {
                    int m = half * 16 + quad * 4 + rr;
                    float rg = sigf(aR[rr] + bgr);
                    float zg = sigf(aZ[rr] + bgz);
                    float cg = tanh_fast(aN[rr] + bxv + rg * (aH[rr] + bhv));
                    float hold = bf2f(src[m * KA_S + 128 + d]);
                    float hv = (1.f - zg) * cg + zg * hold;
                    if (m >= nr) hv = 0.f;
                    dst[m * KA_S + 128 + d] = f2bf(hv);
                }
            }
        }
        __syncthreads();
    }

    // ---- readout: hid = relu(h2 @ Wro^T + ro_b1), h2 in bufA ----
    {
        int s = wave >> 1, mi = wave & 1;
        floatx4 acc = {};
        const short* bw = Wro + (s * 16 + lrow) * KHW + quad * 8;
        const short* ap = bufA + (mi * 16 + lrow) * KA_S + 128 + quad * 8;
        for (int kk = 0; kk < 9; ++kk) {
            short8 a0 = *(const short8*)(ap + kk * 32);
            short8 bv = *(const short8*)(bw + kk * 32);
            acc = MFMA(a0, bv, acc, 0, 0, 0);
        }
        int col = s * 16 + lrow;
        float bias = ro_b1g[col];
#pragma unroll
        for (int rr = 0; rr < 4; ++rr)
            hidL[(mi * 16 + quad * 4 + rr) * 136 + col] = f2bf(fmaxf(acc[rr] + bias, 0.f));
    }
    __syncthreads();

    // ---- final: pred = hid @ ro_w2^T + ro_b2 (waves 0,1) ----
    if (wave < 2) {
        floatx4 acc = {};
        const short* ap = hidL + (wave * 16 + lrow) * 136 + quad * 8;
        const short* bw = Wro2 + lrow * 128 + quad * 8;
        for (int kk = 0; kk < 4; ++kk) {
            short8 a0 = *(const short8*)(ap + kk * 32);
            short8 bv = *(const short8*)(bw + kk * 32);
            acc = MFMA(a0, bv, acc, 0, 0, 0);
        }
        int q = lrow;
        if (q < NCLS) {
            float bias = ro_b2g[q];
#pragma unroll
            for (int rr = 0; rr < 4; ++rr) {
                int m = wave * 16 + quad * 4 + rr;
                float v = acc[rr] + bias;
                if (m >= nr) v = 0.f;
                pred[((size_t)(b * 32 + m)) * NCLS + q] = v;
            }
        }
    }
}

// ---------------------------------------------------------------------------
extern "C" void kernel_launch(void* const* d_in, const int* in_sizes, int n_in,
                              void* d_out, int out_size, void* d_ws, size_t ws_size,
                              hipStream_t stream)
{
    const float* nodes = (const float*)d_in[0];
    const float* pos   = (const float*)d_in[1];
    const int*   nrec  = (const int*)d_in[2];
    const float* w1    = (const float*)d_in[3];
    const float* b1    = (const float*)d_in[4];
    const float* w2    = (const float*)d_in[5];
    const float* b2    = (const float*)d_in[6];
    const float* msg_w = (const float*)d_in[7];
    const float* msg_b = (const float*)d_in[8];
    const float* w_ih  = (const float*)d_in[9];
    const float* w_hh  = (const float*)d_in[10];
    const float* b_ih  = (const float*)d_in[11];
    const float* b_hh  = (const float*)d_in[12];
    const float* ro_w1 = (const float*)d_in[13];
    const float* ro_b1 = (const float*)d_in[14];
    const float* ro_w2 = (const float*)d_in[15];
    const float* ro_b2 = (const float*)d_in[16];
    float* ws   = (float*)d_ws;
    float* pred = (float*)d_out;
    float* attout = pred + (size_t)N_G * M_N * NCLS;

    prep_kernel<<<256, 256, 0, stream>>>(w1, msg_w, w_ih, w_hh, ro_w1, ro_w2,
                                         b_ih, b_hh, ws);
    fused_kernel<<<N_G, 1024, 0, stream>>>(nodes, pos, nrec, b1, w2, b2, msg_b,
                                           ro_b1, ro_b2, ws, attout, pred);
}